// Round 9
// baseline (2173.960 us; speedup 1.0000x reference)
//
#include <hip/hip_runtime.h>
#include <hip/hip_bf16.h>
#include <math.h>

#define B 256
#define S 128
#define I_DIM 512
#define H 1024
#define C 10
#define WROW 1536

#define LDS_H 131072                 // 64 b-rows x 1024 k bf16, XOR-swizzled
#define REDOFF 131072                // 32 KB f32 partial-sum exchange
#define LDS_TOTAL 163840             // exactly 160 KiB

typedef float f32x4 __attribute__((ext_vector_type(4), may_alias));
typedef __bf16 bf16x8 __attribute__((ext_vector_type(8), may_alias));
typedef unsigned int u32x4 __attribute__((ext_vector_type(4), may_alias));
typedef unsigned long long u64;

__device__ __forceinline__ unsigned short f2bf(float f) {
    union { float f; unsigned u; } a; a.f = f;
    return (unsigned short)((a.u + 0x7fffu + ((a.u >> 16) & 1u)) >> 16);
}
__device__ __forceinline__ float sigf(float v) { return 1.0f / (1.0f + __expf(-v)); }
__device__ __forceinline__ float tanh_fast(float v) { return 1.0f - 2.0f / (1.0f + __expf(2.0f * v)); }

// ---- prep 1: W recurrent part -> bf16 in exact MFMA-fragment stream order ----
__global__ void wf_build(const float* __restrict__ fwd_W,
                         const float* __restrict__ bwd_W,
                         __hip_bfloat16* __restrict__ wF) {
    int gid = blockIdx.x * 256 + threadIdx.x;   // 2*256*32*64
    int lane = gid & 63, kk = (gid >> 6) & 31, nsub = (gid >> 11) & 255, d = gid >> 19;
    int n_gl = nsub * 16 + (lane & 15);
    int j = n_gl >> 2, g = n_gl & 3;
    int k = kk * 32 + (lane >> 4) * 8;
    const float* W = d ? bwd_W : fwd_W;
    const float* src = W + (size_t)(g * 1024 + j) * WROW + I_DIM + k;
    ushort4 lo = make_ushort4(f2bf(src[0]), f2bf(src[1]), f2bf(src[2]), f2bf(src[3]));
    ushort4 hi = make_ushort4(f2bf(src[4]), f2bf(src[5]), f2bf(src[6]), f2bf(src[7]));
    ushort4* dst = (ushort4*)(wF + (size_t)gid * 8);
    dst[0] = lo; dst[1] = hi;
}

// ---- prep 2: projP[d][j][v][g] (f32) vectorized; stride 516 (conflict-light) ----
__global__ void projp_kernel(const float* __restrict__ embed,
                             const float* __restrict__ fwd_W,
                             const float* __restrict__ fwd_b,
                             const float* __restrict__ bwd_W,
                             const float* __restrict__ bwd_b,
                             float* __restrict__ projP) {
    __shared__ float wrows[16][516];
    int d  = blockIdx.x >> 8;
    int nc = blockIdx.x & 255;
    int n0 = nc * 16;
    const float* W    = d ? bwd_W : fwd_W;
    const float* bias = d ? bwd_b : fwd_b;
    int tid = threadIdx.x;
    for (int i = tid; i < 16 * 128; i += 256) {
        int r = i >> 7, kc = i & 127;
        *(f32x4*)&wrows[r][kc * 4] = *(const f32x4*)(W + (size_t)(n0 + r) * WROW + kc * 4);
    }
    __syncthreads();
    const int r = tid & 15, vg = tid >> 4;
    const float* eb = embed + (size_t)(vg * 8) * I_DIM;
    f32x4 acc[8] = {};
    for (int kc = 0; kc < 128; kc++) {
        f32x4 w = *(const f32x4*)&wrows[r][kc * 4];
#pragma unroll
        for (int vi = 0; vi < 8; vi++) {
            f32x4 e = *(const f32x4*)(eb + (size_t)vi * I_DIM + kc * 4);
            acc[vi] += w * e;
        }
    }
    const int n = n0 + r, g = n >> 10, j = n & 1023;
    const float bv = bias[n];
    float* outp = projP + ((size_t)d * 1024 + j) * 128 * 4 + g;
#pragma unroll
    for (int vi = 0; vi < 8; vi++) {
        float s = acc[vi][0] + acc[vi][1] + acc[vi][2] + acc[vi][3] + bv;
        outp[(vg * 8 + vi) * 4] = s;
    }
}

// stage 8 x 16B chunks of h from global (L3-coherent sc0 sc1) into swizzled LDS
__device__ __forceinline__ void stage8(const __hip_bfloat16* hr, int r0, int cc,
                                       char* smem, int ibase) {
    const void* p0 = (const void*)(hr + (size_t)((ibase + 0) * 4 + r0) * H + cc * 8);
    const void* p1 = (const void*)(hr + (size_t)((ibase + 1) * 4 + r0) * H + cc * 8);
    const void* p2 = (const void*)(hr + (size_t)((ibase + 2) * 4 + r0) * H + cc * 8);
    const void* p3 = (const void*)(hr + (size_t)((ibase + 3) * 4 + r0) * H + cc * 8);
    const void* p4 = (const void*)(hr + (size_t)((ibase + 4) * 4 + r0) * H + cc * 8);
    const void* p5 = (const void*)(hr + (size_t)((ibase + 5) * 4 + r0) * H + cc * 8);
    const void* p6 = (const void*)(hr + (size_t)((ibase + 6) * 4 + r0) * H + cc * 8);
    const void* p7 = (const void*)(hr + (size_t)((ibase + 7) * 4 + r0) * H + cc * 8);
    u32x4 s0, s1, s2, s3, s4, s5, s6, s7;
    asm volatile(
        "global_load_dwordx4 %0, %8, off sc0 sc1\n\t"
        "global_load_dwordx4 %1, %9, off sc0 sc1\n\t"
        "global_load_dwordx4 %2, %10, off sc0 sc1\n\t"
        "global_load_dwordx4 %3, %11, off sc0 sc1\n\t"
        "global_load_dwordx4 %4, %12, off sc0 sc1\n\t"
        "global_load_dwordx4 %5, %13, off sc0 sc1\n\t"
        "global_load_dwordx4 %6, %14, off sc0 sc1\n\t"
        "global_load_dwordx4 %7, %15, off sc0 sc1\n\t"
        "s_waitcnt vmcnt(0)"
        : "=&v"(s0), "=&v"(s1), "=&v"(s2), "=&v"(s3),
          "=&v"(s4), "=&v"(s5), "=&v"(s6), "=&v"(s7)
        : "v"(p0), "v"(p1), "v"(p2), "v"(p3), "v"(p4), "v"(p5), "v"(p6), "v"(p7)
        : "memory");
    int row;
    row = (ibase + 0) * 4 + r0; *(u32x4*)(smem + row * 2048 + ((cc * 16) ^ ((row & 7) << 4))) = s0;
    row = (ibase + 1) * 4 + r0; *(u32x4*)(smem + row * 2048 + ((cc * 16) ^ ((row & 7) << 4))) = s1;
    row = (ibase + 2) * 4 + r0; *(u32x4*)(smem + row * 2048 + ((cc * 16) ^ ((row & 7) << 4))) = s2;
    row = (ibase + 3) * 4 + r0; *(u32x4*)(smem + row * 2048 + ((cc * 16) ^ ((row & 7) << 4))) = s3;
    row = (ibase + 4) * 4 + r0; *(u32x4*)(smem + row * 2048 + ((cc * 16) ^ ((row & 7) << 4))) = s4;
    row = (ibase + 5) * 4 + r0; *(u32x4*)(smem + row * 2048 + ((cc * 16) ^ ((row & 7) << 4))) = s5;
    row = (ibase + 6) * 4 + r0; *(u32x4*)(smem + row * 2048 + ((cc * 16) ^ ((row & 7) << 4))) = s6;
    row = (ibase + 7) * 4 + r0; *(u32x4*)(smem + row * 2048 + ((cc * 16) ^ ((row & 7) << 4))) = s7;
}

// ---- persistent bi-LSTM: W in registers, K-split-2 waves ----
// 256 blocks x 512 thr. block=(d,bt,jt): 64 b x 32 j (128 n). 8 waves =
// 4 n-groups (8 j) x 2 k-halves (512 k). W frags: 128 VGPR/thread, loaded once.
// kq=1 waves write f32 partials to redbuf; kq=0 reduce + gates + h store.
__global__ __launch_bounds__(512, 2) void bilstm_persistent(
        const int* __restrict__ x,
        const __hip_bfloat16* __restrict__ wF,
        const float* __restrict__ projP,
        __hip_bfloat16* __restrict__ hbuf,   // [2 parity][2 d][256 b][1024 j]
        unsigned* __restrict__ flags) {      // [S][8] slots, stride 16 u32
    extern __shared__ char smem[];
    const int bid = blockIdx.x;
    const int d = bid >> 7, bt = (bid >> 5) & 3, jt = bid & 31;
    const int tid = threadIdx.x, wid = tid >> 6, lane = tid & 63;
    const int kq = wid & 1, ngrp = wid >> 1;
    const int l15 = lane & 15, l4 = lane >> 4;
    const int b0 = bt * 64;
    const size_t dBH = (size_t)d * B * H;

    // ---- persistent W fragments: 2 n-subtiles x 16 kk (128 VGPRs) ----
    bf16x8 wfr[2][16];
#pragma unroll
    for (int nt = 0; nt < 2; nt++)
#pragma unroll
        for (int kk = 0; kk < 16; kk++)
            wfr[nt][kk] = *(const bf16x8*)(wF +
                ((size_t)(d * 256 + jt * 8 + ngrp * 2 + nt) * 32 + kq * 16 + kk) * 512
                + lane * 8);

    int brow[4], bswz[4];
#pragma unroll
    for (int bs = 0; bs < 4; bs++) {
        int row = bs * 16 + l15;
        brow[bs] = row * 2048;
        bswz[bs] = (row & 7) << 4;
    }
    const int r0 = tid >> 7, cc = tid & 127;
    const int jb = jt * 32 + ngrp * 8;
    float cst[2][4] = {};

    for (int t = 0; t < S; t++) {
        if (t > 0) {
            if (tid == 0) {
                const unsigned* p = flags + (size_t)((t - 1) * 8 + d * 4 + bt) * 16;
                while (__hip_atomic_load(p, __ATOMIC_RELAXED, __HIP_MEMORY_SCOPE_AGENT) < 32u)
                    __builtin_amdgcn_s_sleep(4);
            }
            __syncthreads();
        }

        const int tt = d ? (S - 1 - t) : t;
        int vv[4];
        if (!kq) {
#pragma unroll
            for (int bs = 0; bs < 4; bs++)
                vv[bs] = x[(b0 + bs * 16 + l15) * S + tt];
        }

        if (t > 0) {
            const __hip_bfloat16* hr = hbuf + (size_t)(t & 1) * 2 * B * H + dBH + (size_t)b0 * H;
            stage8(hr, r0, cc, smem, 0);
            stage8(hr, r0, cc, smem, 8);
            __syncthreads();
        }

        f32x4 acc[2][4] = {};
        if (t > 0) {
            const int kob = kq * 1024;
#pragma unroll
            for (int kk = 0; kk < 16; kk++) {
                bf16x8 Bf[4];
                const int koff = kob + kk * 64 + l4 * 16;
#pragma unroll
                for (int bs = 0; bs < 4; bs++)
                    Bf[bs] = *(const bf16x8*)(smem + brow[bs] + (koff ^ bswz[bs]));
#pragma unroll
                for (int nt = 0; nt < 2; nt++)
#pragma unroll
                    for (int bs = 0; bs < 4; bs++)
                        acc[nt][bs] = __builtin_amdgcn_mfma_f32_16x16x32_bf16(
                            wfr[nt][kk], Bf[bs], acc[nt][bs], 0, 0, 0);
            }
            if (kq) {
#pragma unroll
                for (int nt = 0; nt < 2; nt++)
#pragma unroll
                    for (int bs = 0; bs < 4; bs++)
                        *(f32x4*)(smem + REDOFF +
                                  ((ngrp * 8 + nt * 4 + bs) * 64 + lane) * 16) = acc[nt][bs];
            }
            __syncthreads();
            if (!kq) {
#pragma unroll
                for (int nt = 0; nt < 2; nt++)
#pragma unroll
                    for (int bs = 0; bs < 4; bs++)
                        acc[nt][bs] += *(const f32x4*)(smem + REDOFF +
                                  ((ngrp * 8 + nt * 4 + bs) * 64 + lane) * 16);
            }
        }

        if (!kq) {
            unsigned o8[4];
#pragma unroll
            for (int nt = 0; nt < 2; nt++) {
                const int jj = jb + nt * 4 + l4;
                const f32x4* pp = (const f32x4*)projP + ((size_t)d * 1024 + jj) * 128;
                float hnv[4];
#pragma unroll
                for (int bs = 0; bs < 4; bs++) {
                    f32x4 pj = pp[vv[bs]];
                    float zg = acc[nt][bs][0] + pj[0];
                    float zi = acc[nt][bs][1] + pj[1];
                    float zf = acc[nt][bs][2] + pj[2];
                    float zo = acc[nt][bs][3] + pj[3];
                    float gg = tanh_fast(zg);
                    float ii = sigf(zi);
                    float ff = sigf(zf);
                    float oo = sigf(zo);
                    float cn = gg * ii + cst[nt][bs] * ff;
                    cst[nt][bs] = cn;
                    hnv[bs] = tanh_fast(cn) * oo;
                }
                // register shfl transpose (verified r6-r8 pattern)
                unsigned plo = (unsigned)f2bf(hnv[0]) | ((unsigned)f2bf(hnv[1]) << 16);
                unsigned phi = (unsigned)f2bf(hnv[2]) | ((unsigned)f2bf(hnv[3]) << 16);
                unsigned short o4[4];
#pragma unroll
                for (int p = 0; p < 4; p++) {
                    int src = p * 16 + l15;
                    unsigned vlo = __shfl(plo, src);
                    unsigned vhi = __shfl(phi, src);
                    unsigned sel = (l4 < 2) ? vlo : vhi;
                    o4[p] = (l4 & 1) ? (unsigned short)(sel >> 16)
                                     : (unsigned short)(sel & 0xffffu);
                }
                o8[nt * 2 + 0] = (unsigned)o4[0] | ((unsigned)o4[1] << 16);
                o8[nt * 2 + 1] = (unsigned)o4[2] | ((unsigned)o4[3] << 16);
            }
            u32x4 hv = {o8[0], o8[1], o8[2], o8[3]};
            void* hw = (void*)(hbuf + (size_t)((t + 1) & 1) * 2 * B * H + dBH
                               + (size_t)(b0 + lane) * H + jt * 32 + ngrp * 8);
            asm volatile("global_store_dwordx4 %0, %1, off sc0 sc1"
                         :: "v"(hw), "v"(hv) : "memory");
        }

        __syncthreads();
        if (tid == 0)
            __hip_atomic_fetch_add(flags + (size_t)(t * 8 + d * 4 + bt) * 16, 1u,
                                   __ATOMIC_RELAXED, __HIP_MEMORY_SCOPE_AGENT);
    }
}

// ---- head: logits + log_softmax (reads bf16 h, parity 0) ----
__global__ void head_kernel(const __hip_bfloat16* __restrict__ hbuf,
                            const float* __restrict__ p_w,
                            const float* __restrict__ p_b,
                            float* __restrict__ out) {
    int b = blockIdx.x;
    int lane = threadIdx.x;  // 64
    float part[C];
#pragma unroll
    for (int cc = 0; cc < C; cc++) part[cc] = 0.0f;
    for (int jj = lane; jj < 2 * H; jj += 64) {
        float hv = (jj < H)
            ? __bfloat162float(hbuf[(size_t)b * H + jj])
            : __bfloat162float(hbuf[(size_t)B * H + (size_t)b * H + jj - H]);
#pragma unroll
        for (int cc = 0; cc < C; cc++) part[cc] += hv * p_w[cc * 2 * H + jj];
    }
#pragma unroll
    for (int cc = 0; cc < C; cc++) {
        float v = part[cc];
        for (int off = 32; off; off >>= 1) v += __shfl_down(v, off);
        part[cc] = v;
    }
    if (lane == 0) {
        float lg[C];
        float m = -1e30f;
        for (int cc = 0; cc < C; cc++) {
            lg[cc] = part[cc] + p_b[cc];
            m = fmaxf(m, lg[cc]);
        }
        float s = 0.0f;
        for (int cc = 0; cc < C; cc++) s += expf(lg[cc] - m);
        float lse = logf(s) + m;
        for (int cc = 0; cc < C; cc++) out[b * C + cc] = lg[cc] - lse;
    }
}

extern "C" void kernel_launch(void* const* d_in, const int* in_sizes, int n_in,
                              void* d_out, int out_size, void* d_ws, size_t ws_size,
                              hipStream_t stream) {
    const int*   x     = (const int*)d_in[0];
    const float* embed = (const float*)d_in[1];
    const float* fwd_W = (const float*)d_in[2];
    const float* fwd_b = (const float*)d_in[3];
    const float* bwd_W = (const float*)d_in[4];
    const float* bwd_b = (const float*)d_in[5];
    const float* p_w   = (const float*)d_in[6];
    const float* p_b   = (const float*)d_in[7];
    float* outp = (float*)d_out;

    char* ws = (char*)d_ws;
    __hip_bfloat16* wF = (__hip_bfloat16*)ws;  ws += (size_t)2 * 256 * 16384 * 2;     // 16 MB
    float* projP = (float*)ws;                 ws += (size_t)2 * 1024 * 128 * 4 * 4;  // 4 MB
    __hip_bfloat16* hbuf = (__hip_bfloat16*)ws; ws += (size_t)2 * 2 * B * H * 2;      // 2 MB
    unsigned* flags = (unsigned*)ws;           ws += (size_t)S * 8 * 16 * 4;          // 64 KB

    hipMemsetAsync(flags, 0, (size_t)S * 8 * 16 * 4, stream);
    hipLaunchKernelGGL(wf_build, dim3(4096), dim3(256), 0, stream, fwd_W, bwd_W, wF);
    hipLaunchKernelGGL(projp_kernel, dim3(512), dim3(256), 0, stream,
                       embed, fwd_W, fwd_b, bwd_W, bwd_b, projP);

    hipFuncSetAttribute((const void*)bilstm_persistent,
                        hipFuncAttributeMaxDynamicSharedMemorySize, LDS_TOTAL);

    void* args[] = {(void*)&x, (void*)&wF, (void*)&projP, (void*)&hbuf, (void*)&flags};
    hipLaunchCooperativeKernel((void*)bilstm_persistent, dim3(256), dim3(512),
                               args, LDS_TOTAL, stream);

    hipLaunchKernelGGL(head_kernel, dim3(B), dim3(64), 0, stream,
                       hbuf, p_w, p_b, outp);
}